// Round 1
// baseline (465.321 us; speedup 1.0000x reference)
//
#include <hip/hip_runtime.h>
#include <math.h>

// Modulated deformable conv2d, B=4, C=O=64, H=W=128, K=3, stride=1, pad=1.
//
// Pipeline (4 kernels, all on `stream`):
//   prep_weights : weight[O][C][3][3] -> wt4[k][c/4][o][4]  (main GEMM layout)
//                  w_off[27][32][3][3] -> wt_off[ic][tap][28] (scalar-load layout)
//   transpose_x  : x NCHW -> xt NHWC (coalesced channel gathers for sampling)
//   offset_conv  : om = conv(offset_feat, w_off)+b_off; writes per-pixel packed
//                  off_buf[pix][k][4] = {dy, dx, sigmoid(m), pad}
//   deform_main  : per wave: 16 pixels; lane=c samples bilinear (mask+validity
//                  folded into corner coeffs), LDS broadcast, lane=o matvec with
//                  per-tap weights in VGPRs. acc over 9 taps, + bias, store NCHW.
//
// ws layout (floats):
//   xt      @ 0         : 4*128*128*64      = 4,194,304
//   off_buf @ 4194304   : 65536*36          = 2,359,296
//   wt4     @ 6553600   : 9*16*64*4         = 36,864
//   wt_off  @ 6590464   : 32*9*28           = 8,064
//   total ~26.4 MB

#define NB 4
#define NC 64
#define NH 128
#define NW 128
#define OFFC 32

__global__ __launch_bounds__(256) void prep_weights(
        const float* __restrict__ weight, const float* __restrict__ w_off,
        float* __restrict__ wt4, float* __restrict__ wt_off) {
    int idx = blockIdx.x * 256 + threadIdx.x;
    if (idx < 9 * 16 * 64 * 4) {
        int j  = idx & 3;
        int o  = (idx >> 2) & 63;
        int cq = (idx >> 8) & 15;
        int k  = idx >> 12;
        int c  = cq * 4 + j;
        // weight[o][c][ky][kx], k = ky*3+kx
        wt4[idx] = weight[(o * 64 + c) * 9 + k];
    }
    int idx2 = idx - 9 * 16 * 64 * 4;
    if (idx2 >= 0 && idx2 < 32 * 9 * 28) {
        int oc  = idx2 % 28;
        int r   = idx2 / 28;
        int tap = r % 9;
        int ic  = r / 9;
        wt_off[idx2] = (oc < 27) ? w_off[(oc * 32 + ic) * 9 + tap] : 0.0f;
    }
}

__global__ __launch_bounds__(256) void transpose_x(
        const float* __restrict__ x, float* __restrict__ xt) {
    // one block per (b, y) row; LDS pad 130 -> conflict-free both phases
    __shared__ float lds[64][130];
    int b = blockIdx.x >> 7;
    int y = blockIdx.x & 127;
    int t = threadIdx.x;
    int xx = t & 127;
    int c0 = t >> 7;  // 0..1
#pragma unroll
    for (int it = 0; it < 32; ++it) {
        int c = it * 2 + c0;
        lds[c][xx] = x[((b * 64 + c) * 128 + y) * 128 + xx];
    }
    __syncthreads();
#pragma unroll
    for (int it = 0; it < 32; ++it) {
        int flat = it * 256 + t;
        int c  = flat & 63;
        int x2 = flat >> 6;
        xt[((b * 128 + y) * 128 + x2) * 64 + c] = lds[c][x2];
    }
}

__global__ __launch_bounds__(256) void offset_conv(
        const float* __restrict__ feat, const float* __restrict__ wt_off,
        const float* __restrict__ b_off, float* __restrict__ off_buf) {
    // one wave = 64 consecutive pixels (same row), all 27 output channels.
    // weights via wave-uniform indices -> scalar loads, FMA with SGPR operand.
    int gw   = (blockIdx.x * 256 + threadIdx.x) >> 6;
    int lane = threadIdx.x & 63;
    int pix  = gw * 64 + lane;
    int b = pix >> 14;
    int y = (pix >> 7) & 127;
    int x = pix & 127;
    float acc[27];
#pragma unroll
    for (int o = 0; o < 27; ++o) acc[o] = b_off[o];
    for (int ic = 0; ic < 32; ++ic) {
        float v[9];
#pragma unroll
        for (int kh = 0; kh < 3; ++kh) {
#pragma unroll
            for (int kw = 0; kw < 3; ++kw) {
                int yy = y - 1 + kh;
                int xx = x - 1 + kw;
                float valid = (yy >= 0 && yy < NH && xx >= 0 && xx < NW) ? 1.0f : 0.0f;
                int yyc = min(max(yy, 0), NH - 1);
                int xxc = min(max(xx, 0), NW - 1);
                v[kh * 3 + kw] = feat[((b * OFFC + ic) * NH + yyc) * NW + xxc] * valid;
            }
        }
#pragma unroll
        for (int tap = 0; tap < 9; ++tap) {
#pragma unroll
            for (int o = 0; o < 27; ++o) {
                acc[o] = fmaf(v[tap], wt_off[(ic * 9 + tap) * 28 + o], acc[o]);
            }
        }
    }
#pragma unroll
    for (int o = 0; o < 27; ++o) {
        float val = acc[o];
        int slot;
        if (o < 18) {                 // dy_k = om[2k], dx_k = om[2k+1]
            int k = o >> 1;
            slot = k * 4 + (o & 1);
        } else {                      // mask_k = sigmoid(om[18+k])
            int k = o - 18;
            slot = k * 4 + 2;
            val = 1.0f / (1.0f + __expf(-val));
        }
        off_buf[pix * 36 + slot] = val;
    }
}

__global__ __launch_bounds__(256) void deform_main(
        const float* __restrict__ xt, const float* __restrict__ off_buf,
        const float* __restrict__ wt4, const float* __restrict__ bias,
        float* __restrict__ out) {
    __shared__ __align__(16) float s_lds[4][2][64];
    int widx = threadIdx.x >> 6;
    int lane = threadIdx.x & 63;
    int gw   = blockIdx.x * 4 + widx;
    int pix0 = gw * 16;                    // 16 consecutive pixels, same row
    int b  = pix0 >> 14;
    int y  = (pix0 >> 7) & 127;
    int x0 = pix0 & 127;
    float bv = bias[lane];
    float acc[16];
#pragma unroll
    for (int p = 0; p < 16; ++p) acc[p] = bv;

    const float* xb = xt + (size_t)b * (NH * NW * NC);

    for (int k = 0; k < 9; ++k) {
        float kyf = (float)(k / 3) - 1.0f + (float)y;
        float kxf = (float)(k % 3) - 1.0f + (float)x0;
        // per-tap weight fragment: lane=o holds w[k][c][o] for c=0..63
        float4 wq[16];
#pragma unroll
        for (int cq = 0; cq < 16; ++cq)
            wq[cq] = *reinterpret_cast<const float4*>(&wt4[(k * 16 + cq) * 256 + lane * 4]);

#pragma unroll
        for (int p = 0; p < 16; ++p) {
            int pix = pix0 + p;
            float4 off = *reinterpret_cast<const float4*>(&off_buf[pix * 36 + k * 4]);
            float py = kyf + off.x;
            float px = kxf + (float)p + off.y;
            float m  = off.z;
            float y0f = floorf(py), x0f = floorf(px);
            float wy = py - y0f, wx = px - x0f;
            int iy0 = (int)y0f, ix0 = (int)x0f;
            int iy1 = iy0 + 1, ix1 = ix0 + 1;
            float vy0 = (iy0 >= 0 && iy0 < NH) ? 1.0f : 0.0f;
            float vy1 = (iy1 >= 0 && iy1 < NH) ? 1.0f : 0.0f;
            float vx0 = (ix0 >= 0 && ix0 < NW) ? 1.0f : 0.0f;
            float vx1 = (ix1 >= 0 && ix1 < NW) ? 1.0f : 0.0f;
            int iy0c = min(max(iy0, 0), NH - 1), iy1c = min(max(iy1, 0), NH - 1);
            int ix0c = min(max(ix0, 0), NW - 1), ix1c = min(max(ix1, 0), NW - 1);
            float c00 = (1.0f - wy) * (1.0f - wx) * m * vy0 * vx0;
            float c01 = (1.0f - wy) * wx * m * vy0 * vx1;
            float c10 = wy * (1.0f - wx) * m * vy1 * vx0;
            float c11 = wy * wx * m * vy1 * vx1;
            // lane = channel c: coalesced 256B gathers from NHWC
            float v00 = xb[(iy0c * NW + ix0c) * NC + lane];
            float v01 = xb[(iy0c * NW + ix1c) * NC + lane];
            float v10 = xb[(iy1c * NW + ix0c) * NC + lane];
            float v11 = xb[(iy1c * NW + ix1c) * NC + lane];
            float s = c00 * v00 + c01 * v01 + c10 * v10 + c11 * v11;
            s_lds[widx][p & 1][lane] = s;
            // same-wave RAW through LDS: drain before cross-lane reads
            __asm__ volatile("s_waitcnt lgkmcnt(0)" ::: "memory");
#pragma unroll
            for (int cq = 0; cq < 16; ++cq) {
                float4 sv = *reinterpret_cast<const float4*>(&s_lds[widx][p & 1][cq * 4]);
                acc[p] = fmaf(sv.x, wq[cq].x, acc[p]);
                acc[p] = fmaf(sv.y, wq[cq].y, acc[p]);
                acc[p] = fmaf(sv.z, wq[cq].z, acc[p]);
                acc[p] = fmaf(sv.w, wq[cq].w, acc[p]);
            }
            __asm__ volatile("" ::: "memory");
        }
    }
#pragma unroll
    for (int p = 0; p < 16; ++p) {
        out[((b * 64 + lane) * NH + y) * NW + x0 + p] = acc[p];
    }
}

extern "C" void kernel_launch(void* const* d_in, const int* in_sizes, int n_in,
                              void* d_out, int out_size, void* d_ws, size_t ws_size,
                              hipStream_t stream) {
    const float* x        = (const float*)d_in[0];
    const float* off_feat = (const float*)d_in[1];
    const float* w_off    = (const float*)d_in[2];
    const float* b_off    = (const float*)d_in[3];
    const float* weight   = (const float*)d_in[4];
    const float* bias     = (const float*)d_in[5];
    float* out = (float*)d_out;

    float* ws      = (float*)d_ws;
    float* xt      = ws;                    // 4,194,304
    float* off_buf = ws + 4194304;          // 2,359,296
    float* wt4     = ws + 6553600;          // 36,864
    float* wt_off  = ws + 6590464;          // 8,064

    prep_weights<<<176, 256, 0, stream>>>(weight, w_off, wt4, wt_off);
    transpose_x<<<512, 256, 0, stream>>>(x, xt);
    offset_conv<<<256, 256, 0, stream>>>(off_feat, wt_off, b_off, off_buf);
    deform_main<<<1024, 256, 0, stream>>>(xt, off_buf, wt4, bias, out);
}

// Round 2
// 257.584 us; speedup vs baseline: 1.8065x; 1.8065x over previous
//
#include <hip/hip_runtime.h>
#include <math.h>

typedef unsigned short ushort_t;
typedef unsigned int uint_t;
typedef __attribute__((ext_vector_type(8))) short short8;
typedef __attribute__((ext_vector_type(4))) float f32x4;

#define NB 4
#define NC 64
#define NH 128
#define NW 128
#define OFFC 32

// ws layout (float units):
//   xt      @ 0        : 4*128*128*64 = 4,194,304
//   off_buf @ 4194304  : 65536*36     = 2,359,296
//   wt_off  @ 6553600  : 32*9*28      = 8,064
//   g_wbh   @ 6561664  : 9*64*72 ushort = 20,736 floats
//   g_wbl   @ 6582400  : 20,736 floats
//   end 6,603,136 floats (~26.4 MB)

__device__ __forceinline__ void async_copy16(void* lds_dst, const void* g_src) {
    __builtin_amdgcn_global_load_lds(
        (const __attribute__((address_space(1))) unsigned int*)g_src,
        (__attribute__((address_space(3))) unsigned int*)lds_dst, 16, 0, 0);
}

__device__ __forceinline__ void split_bf16(float v, ushort_t& h, ushort_t& l) {
    uint_t bb = __float_as_uint(v);
    uint_t rr = bb + 0x7fffu + ((bb >> 16) & 1u);   // RNE for hi
    h = (ushort_t)(rr >> 16);
    float hf = __uint_as_float(((uint_t)h) << 16);
    float lof = v - hf;                              // exact
    l = (ushort_t)(__float_as_uint(lof) >> 16);      // truncate lo
}

__global__ __launch_bounds__(256) void prep_weights(
        const float* __restrict__ weight, const float* __restrict__ w_off,
        ushort_t* __restrict__ g_wbh, ushort_t* __restrict__ g_wbl,
        float* __restrict__ wt_off) {
    int idx = blockIdx.x * 256 + threadIdx.x;
    if (idx < 9 * 64 * 72) {
        int k   = idx % 72;            // channel c (pad 64..71 -> 0)
        int o   = (idx / 72) % 64;
        int tap = idx / (72 * 64);
        float v = (k < 64) ? weight[(o * 64 + k) * 9 + tap] : 0.0f;
        ushort_t h, l;
        split_bf16(v, h, l);
        g_wbh[idx] = h;
        g_wbl[idx] = l;
    }
    int idx2 = idx - 9 * 64 * 72;
    if (idx2 >= 0 && idx2 < 32 * 9 * 28) {
        int oc  = idx2 % 28;
        int r   = idx2 / 28;
        int tap = r % 9;
        int ic  = r / 9;
        wt_off[idx2] = (oc < 27) ? w_off[(oc * 32 + ic) * 9 + tap] : 0.0f;
    }
}

__global__ __launch_bounds__(256) void transpose_x(
        const float* __restrict__ x, float* __restrict__ xt) {
    __shared__ float lds[64][130];
    int b = blockIdx.x >> 7;
    int y = blockIdx.x & 127;
    int t = threadIdx.x;
    int xx = t & 127;
    int c0 = t >> 7;
#pragma unroll
    for (int it = 0; it < 32; ++it) {
        int c = it * 2 + c0;
        lds[c][xx] = x[((b * 64 + c) * 128 + y) * 128 + xx];
    }
    __syncthreads();
#pragma unroll
    for (int it = 0; it < 32; ++it) {
        int flat = it * 256 + t;
        int c  = flat & 63;
        int x2 = flat >> 6;
        xt[((b * 128 + y) * 128 + x2) * 64 + c] = lds[c][x2];
    }
}

// 4-way ic-split offset conv: block = 64 px, wave w handles ic in [8w, 8w+8)
__global__ __launch_bounds__(256) void offset_conv(
        const float* __restrict__ feat, const float* __restrict__ wt_off,
        const float* __restrict__ b_off, float* __restrict__ off_buf) {
    __shared__ float red[4][27][64];
    int wv = threadIdx.x >> 6, lane = threadIdx.x & 63;
    int pix = blockIdx.x * 64 + lane;
    int b = pix >> 14, y = (pix >> 7) & 127, x = pix & 127;
    float acc[27];
#pragma unroll
    for (int o = 0; o < 27; ++o) acc[o] = 0.0f;
    for (int ic = wv * 8; ic < wv * 8 + 8; ++ic) {
        float v[9];
#pragma unroll
        for (int kh = 0; kh < 3; ++kh) {
#pragma unroll
            for (int kw = 0; kw < 3; ++kw) {
                int yy = y - 1 + kh;
                int xx = x - 1 + kw;
                float valid = (yy >= 0 && yy < NH && xx >= 0 && xx < NW) ? 1.0f : 0.0f;
                int yyc = min(max(yy, 0), NH - 1);
                int xxc = min(max(xx, 0), NW - 1);
                v[kh * 3 + kw] = feat[((b * OFFC + ic) * NH + yyc) * NW + xxc] * valid;
            }
        }
#pragma unroll
        for (int tap = 0; tap < 9; ++tap)
#pragma unroll
            for (int o = 0; o < 27; ++o)
                acc[o] = fmaf(v[tap], wt_off[(ic * 9 + tap) * 28 + o], acc[o]);
    }
#pragma unroll
    for (int o = 0; o < 27; ++o) red[wv][o][lane] = acc[o];
    __syncthreads();
#pragma unroll
    for (int j = 0; j < 7; ++j) {
        int o = wv * 7 + j;
        if (o < 27) {
            float val = red[0][o][lane] + red[1][o][lane] + red[2][o][lane]
                      + red[3][o][lane] + b_off[o];
            int slot; float outv;
            if (o < 18) { int k = o >> 1; slot = k * 4 + (o & 1); outv = val; }
            else        { int k = o - 18; slot = k * 4 + 2; outv = 1.0f / (1.0f + __expf(-val)); }
            off_buf[(size_t)pix * 36 + slot] = outv;
        }
    }
}

// Fused sample + bf16-split MFMA GEMM. Block = one (b,y) row = 128 px, 4 waves.
// Wave w: samples px [32w,32w+32), computes out rows for same px, all 64 o.
// K per tap = 64 (c); 3-term split => 6 MFMA k-steps per tap per 16x16 tile.
__global__ __launch_bounds__(256, 2) void deform_main(
        const float* __restrict__ xt, const float* __restrict__ off_buf,
        const ushort_t* __restrict__ g_wbh, const ushort_t* __restrict__ g_wbl,
        const float* __restrict__ bias, float* __restrict__ out) {
    __shared__ __align__(16) ushort_t s_hi[128][72];       // 18,432 B
    __shared__ __align__(16) ushort_t s_lo[128][72];       // 18,432 B
    __shared__ __align__(16) ushort_t wb[2][2][64][72];    // 36,864 B  [buf][h/l][o][k]

    int w = threadIdx.x >> 6, lane = threadIdx.x & 63;
    int col = lane & 15;          // n-col / m-row low bits for MFMA frags
    int kgrp = lane >> 4;         // 0..3
    int blk = blockIdx.x;
    int b = blk >> 7, y = blk & 127;
    int pix0 = blk * 128;
    const float* xb = xt + (size_t)b * (NH * NW * NC);

    // accumulators init with bias: D col = lane&15 -> o = n*16+col
    f32x4 acc[2][4];
#pragma unroll
    for (int n = 0; n < 4; ++n) {
        float bv = bias[n * 16 + col];
#pragma unroll
        for (int m = 0; m < 2; ++m) acc[m][n] = (f32x4){bv, bv, bv, bv};
    }

    // ---- W prefetch helper (18 x 1024B chunks, round-robin over waves) ----
    auto prefetchW = [&](int tap, int bi) {
        for (int j = w; j < 18; j += 4) {
            int hsel = (j < 9) ? 0 : 1;
            int j2 = (j < 9) ? j : j - 9;
            const ushort_t* src = (hsel ? g_wbl : g_wbh) + tap * 4608 + j2 * 512 + lane * 8;
            ushort_t* dst = &wb[bi][hsel][0][0] + j2 * 512;
            async_copy16(dst, src);
        }
    };

    prefetchW(0, 0);
    __syncthreads();   // drains vmcnt -> W0 ready

    for (int t = 0; t < 9; ++t) {
        int ky = t / 3, kx = t % 3;
        float ybase = (float)(y - 1 + ky);
        // ---- sampling: 32 px per wave, lane = channel ----
#pragma unroll 4
        for (int p = 0; p < 32; ++p) {
            int rowi = w * 32 + p;          // = x coordinate
            int px = pix0 + rowi;
            const float4 off = *(const float4*)(off_buf + (size_t)px * 36 + t * 4);
            float py  = ybase + off.x;
            float pxv = (float)(rowi - 1 + kx) + off.y;
            float y0f = floorf(py), x0f = floorf(pxv);
            float wy = py - y0f, wx = pxv - x0f;
            int iy0 = (int)y0f, ix0 = (int)x0f;
            int iy1 = iy0 + 1, ix1 = ix0 + 1;
            float vy0 = (iy0 >= 0 && iy0 < NH) ? 1.0f : 0.0f;
            float vy1 = (iy1 >= 0 && iy1 < NH) ? 1.0f : 0.0f;
            float vx0 = (ix0 >= 0 && ix0 < NW) ? 1.0f : 0.0f;
            float vx1 = (ix1 >= 0 && ix1 < NW) ? 1.0f : 0.0f;
            int iy0c = min(max(iy0, 0), NH - 1), iy1c = min(max(iy1, 0), NH - 1);
            int ix0c = min(max(ix0, 0), NW - 1), ix1c = min(max(ix1, 0), NW - 1);
            float m  = off.z;
            float c00 = (1.0f - wy) * (1.0f - wx) * vy0 * vx0 * m;
            float c01 = (1.0f - wy) * wx * vy0 * vx1 * m;
            float c10 = wy * (1.0f - wx) * vy1 * vx0 * m;
            float c11 = wy * wx * vy1 * vx1 * m;
            float v00 = xb[(iy0c * NW + ix0c) * NC + lane];
            float v01 = xb[(iy0c * NW + ix1c) * NC + lane];
            float v10 = xb[(iy1c * NW + ix0c) * NC + lane];
            float v11 = xb[(iy1c * NW + ix1c) * NC + lane];
            float s = c00 * v00 + c01 * v01 + c10 * v10 + c11 * v11;
            ushort_t h, l;
            split_bf16(s, h, l);
            s_hi[rowi][lane] = h;
            s_lo[rowi][lane] = l;
        }
        if (t < 8) prefetchW(t + 1, (t + 1) & 1);
        __syncthreads();   // s tiles + W[t] (and prefetch t+1) visible

        // ---- GEMM phase: per wave 2 m-tiles x 4 n-tiles, 6 k-steps ----
        {
            int bi = t & 1;
            short8 bh[4][2], bl[4][2];
#pragma unroll
            for (int n = 0; n < 4; ++n)
#pragma unroll
                for (int ks = 0; ks < 2; ++ks) {
                    bh[n][ks] = *(const short8*)&wb[bi][0][n * 16 + col][ks * 32 + kgrp * 8];
                    bl[n][ks] = *(const short8*)&wb[bi][1][n * 16 + col][ks * 32 + kgrp * 8];
                }
            short8 ah[2][2], al[2][2];
#pragma unroll
            for (int m = 0; m < 2; ++m)
#pragma unroll
                for (int ks = 0; ks < 2; ++ks) {
                    int row = w * 32 + m * 16 + col;
                    ah[m][ks] = *(const short8*)&s_hi[row][ks * 32 + kgrp * 8];
                    al[m][ks] = *(const short8*)&s_lo[row][ks * 32 + kgrp * 8];
                }
#pragma unroll
            for (int m = 0; m < 2; ++m)
#pragma unroll
                for (int n = 0; n < 4; ++n) {
                    acc[m][n] = __builtin_amdgcn_mfma_f32_16x16x32_bf16(ah[m][0], bh[n][0], acc[m][n], 0, 0, 0);
                    acc[m][n] = __builtin_amdgcn_mfma_f32_16x16x32_bf16(ah[m][1], bh[n][1], acc[m][n], 0, 0, 0);
                    acc[m][n] = __builtin_amdgcn_mfma_f32_16x16x32_bf16(ah[m][0], bl[n][0], acc[m][n], 0, 0, 0);
                    acc[m][n] = __builtin_amdgcn_mfma_f32_16x16x32_bf16(ah[m][1], bl[n][1], acc[m][n], 0, 0, 0);
                    acc[m][n] = __builtin_amdgcn_mfma_f32_16x16x32_bf16(al[m][0], bh[n][0], acc[m][n], 0, 0, 0);
                    acc[m][n] = __builtin_amdgcn_mfma_f32_16x16x32_bf16(al[m][1], bh[n][1], acc[m][n], 0, 0, 0);
                }
        }
        __syncthreads();   // GEMM done before next tap overwrites s / W buf
    }

    // ---- store: D row=(lane>>4)*4+r -> x, col -> o; float4 per (m,n) ----
#pragma unroll
    for (int m = 0; m < 2; ++m)
#pragma unroll
        for (int n = 0; n < 4; ++n) {
            int o = n * 16 + col;
            int x = w * 32 + m * 16 + kgrp * 4;
            float* dst = out + (((size_t)(b * 64 + o)) * 128 + y) * 128 + x;
            *(f32x4*)dst = acc[m][n];
        }
}

extern "C" void kernel_launch(void* const* d_in, const int* in_sizes, int n_in,
                              void* d_out, int out_size, void* d_ws, size_t ws_size,
                              hipStream_t stream) {
    const float* x        = (const float*)d_in[0];
    const float* off_feat = (const float*)d_in[1];
    const float* w_off    = (const float*)d_in[2];
    const float* b_off    = (const float*)d_in[3];
    const float* weight   = (const float*)d_in[4];
    const float* bias     = (const float*)d_in[5];
    float* out = (float*)d_out;

    float* ws      = (float*)d_ws;
    float* xt      = ws;                          // 4,194,304
    float* off_buf = ws + 4194304;                // 2,359,296
    float* wt_off  = ws + 6553600;                // 8,064
    ushort_t* g_wbh = (ushort_t*)(ws + 6561664);  // 41,472 ushorts
    ushort_t* g_wbl = (ushort_t*)(ws + 6582400);  // 41,472 ushorts

    prep_weights<<<194, 256, 0, stream>>>(weight, w_off, g_wbh, g_wbl, wt_off);
    transpose_x<<<512, 256, 0, stream>>>(x, xt);
    offset_conv<<<1024, 256, 0, stream>>>(off_feat, wt_off, b_off, off_buf);
    deform_main<<<512, 256, 0, stream>>>(xt, off_buf, g_wbh, g_wbl, bias, out);
}

// Round 4
// 220.753 us; speedup vs baseline: 2.1079x; 1.1668x over previous
//
#include <hip/hip_runtime.h>
#include <math.h>

typedef unsigned short ushort_t;
typedef unsigned int uint_t;
typedef __attribute__((ext_vector_type(8))) short short8;
typedef __attribute__((ext_vector_type(4))) float f32x4;

#define NB 4
#define NC 64
#define NH 128
#define NW 128
#define OFFC 32

// ws layout (float units) — total 6,603,136 floats = 26,412,544 B,
// EXACTLY the round-2 proven footprint (round-3's 31.1 MB layout faulted).
//   xt     @ 0         : 4*128*128*64   = 4,194,304
//   coefA  @ 4194304   : 9*65536*4     = 2,359,296   uint4 per (tap,px)
//                        coef f32 with idx embedded in low 7 mantissa bits:
//                        c00|iy0c, c01|iy1c, c10|ix0c, c11|ix1c
//   wt_off @ 6553600   : 32*9*28       = 8,064
//   g_wbh  @ 6561664   : 9*64*72 ushort = 20,736 floats
//   g_wbl  @ 6582400   : 20,736 floats

__device__ __forceinline__ void async_copy16(void* lds_dst, const void* g_src) {
    __builtin_amdgcn_global_load_lds(
        (const __attribute__((address_space(1))) unsigned int*)g_src,
        (__attribute__((address_space(3))) unsigned int*)lds_dst, 16, 0, 0);
}

__device__ __forceinline__ void split_bf16(float v, ushort_t& h, ushort_t& l) {
    uint_t bb = __float_as_uint(v);
    uint_t rr = bb + 0x7fffu + ((bb >> 16) & 1u);   // RNE for hi
    h = (ushort_t)(rr >> 16);
    float hf = __uint_as_float(((uint_t)h) << 16);
    float lof = v - hf;                              // exact
    l = (ushort_t)(__float_as_uint(lof) >> 16);      // truncate lo
}

__global__ __launch_bounds__(256) void prep_weights(
        const float* __restrict__ weight, const float* __restrict__ w_off,
        ushort_t* __restrict__ g_wbh, ushort_t* __restrict__ g_wbl,
        float* __restrict__ wt_off) {
    int idx = blockIdx.x * 256 + threadIdx.x;
    if (idx < 9 * 64 * 72) {
        int k   = idx % 72;            // channel c (pad 64..71 -> 0)
        int o   = (idx / 72) % 64;
        int tap = idx / (72 * 64);
        float v = (k < 64) ? weight[(o * 64 + k) * 9 + tap] : 0.0f;
        ushort_t h, l;
        split_bf16(v, h, l);
        g_wbh[idx] = h;
        g_wbl[idx] = l;
    }
    int idx2 = idx - 9 * 64 * 72;
    if (idx2 >= 0 && idx2 < 32 * 9 * 28) {
        int oc  = idx2 % 28;
        int r   = idx2 / 28;
        int tap = r % 9;
        int ic  = r / 9;
        wt_off[idx2] = (oc < 27) ? w_off[(oc * 32 + ic) * 9 + tap] : 0.0f;
    }
}

__global__ __launch_bounds__(256) void transpose_x(
        const float* __restrict__ x, float* __restrict__ xt) {
    __shared__ float lds[64][130];
    int b = blockIdx.x >> 7;
    int y = blockIdx.x & 127;
    int t = threadIdx.x;
    int xx = t & 127;
    int c0 = t >> 7;
#pragma unroll
    for (int it = 0; it < 32; ++it) {
        int c = it * 2 + c0;
        lds[c][xx] = x[((b * 64 + c) * 128 + y) * 128 + xx];
    }
    __syncthreads();
#pragma unroll
    for (int it = 0; it < 32; ++it) {
        int flat = it * 256 + t;
        int c  = flat & 63;
        int x2 = flat >> 6;
        xt[((b * 128 + y) * 128 + x2) * 64 + c] = lds[c][x2];
    }
}

// Offset conv + sampling-coefficient precompute with embedded indices.
__global__ __launch_bounds__(256) void offset_conv(
        const float* __restrict__ feat, const float* __restrict__ wt_off,
        const float* __restrict__ b_off, uint_t* __restrict__ coefA) {
    __shared__ float red[4][27][64];
    int wv = threadIdx.x >> 6, lane = threadIdx.x & 63;
    int pix = blockIdx.x * 64 + lane;
    int b = pix >> 14, y = (pix >> 7) & 127, x = pix & 127;
    float acc[27];
#pragma unroll
    for (int o = 0; o < 27; ++o) acc[o] = 0.0f;
    for (int ic = wv * 8; ic < wv * 8 + 8; ++ic) {
        float v[9];
#pragma unroll
        for (int kh = 0; kh < 3; ++kh) {
#pragma unroll
            for (int kw = 0; kw < 3; ++kw) {
                int yy = y - 1 + kh;
                int xx = x - 1 + kw;
                float valid = (yy >= 0 && yy < NH && xx >= 0 && xx < NW) ? 1.0f : 0.0f;
                int yyc = min(max(yy, 0), NH - 1);
                int xxc = min(max(xx, 0), NW - 1);
                v[kh * 3 + kw] = feat[((b * OFFC + ic) * NH + yyc) * NW + xxc] * valid;
            }
        }
#pragma unroll
        for (int tap = 0; tap < 9; ++tap)
#pragma unroll
            for (int o = 0; o < 27; ++o)
                acc[o] = fmaf(v[tap], wt_off[(ic * 9 + tap) * 28 + o], acc[o]);
    }
#pragma unroll
    for (int o = 0; o < 27; ++o) red[wv][o][lane] = acc[o];
    __syncthreads();
    for (int t = wv; t < 9; t += 4) {
        float dy = red[0][2 * t][lane] + red[1][2 * t][lane]
                 + red[2][2 * t][lane] + red[3][2 * t][lane] + b_off[2 * t];
        float dx = red[0][2 * t + 1][lane] + red[1][2 * t + 1][lane]
                 + red[2][2 * t + 1][lane] + red[3][2 * t + 1][lane] + b_off[2 * t + 1];
        float mv = red[0][18 + t][lane] + red[1][18 + t][lane]
                 + red[2][18 + t][lane] + red[3][18 + t][lane] + b_off[18 + t];
        float mm = 1.0f / (1.0f + __expf(-mv));
        float py  = (float)(y - 1 + t / 3) + dy;
        float pxf = (float)(x - 1 + t % 3) + dx;
        float y0f = floorf(py), x0f = floorf(pxf);
        float wy = py - y0f, wx = pxf - x0f;
        int iy0 = (int)y0f, ix0 = (int)x0f;
        int iy1 = iy0 + 1, ix1 = ix0 + 1;
        float vy0 = (iy0 >= 0 && iy0 < NH) ? 1.0f : 0.0f;
        float vy1 = (iy1 >= 0 && iy1 < NH) ? 1.0f : 0.0f;
        float vx0 = (ix0 >= 0 && ix0 < NW) ? 1.0f : 0.0f;
        float vx1 = (ix1 >= 0 && ix1 < NW) ? 1.0f : 0.0f;
        int iy0c = min(max(iy0, 0), NH - 1), iy1c = min(max(iy1, 0), NH - 1);
        int ix0c = min(max(ix0, 0), NW - 1), ix1c = min(max(ix1, 0), NW - 1);
        float c00 = (1.0f - wy) * (1.0f - wx) * vy0 * vx0 * mm;
        float c01 = (1.0f - wy) * wx * vy0 * vx1 * mm;
        float c10 = wy * (1.0f - wx) * vy1 * vx0 * mm;
        float c11 = wy * wx * vy1 * vx1 * mm;
        // coefs are >= 0; stuff clamped indices into low 7 mantissa bits
        // (perturbation <= 127 ulp ~ 1.5e-5 relative -> negligible).
        // NB: iy1c/ix1c stored independently — NOT derivable from iy0c at borders.
        uint_t u00 = (__float_as_uint(c00) & ~127u) | (uint_t)iy0c;
        uint_t u01 = (__float_as_uint(c01) & ~127u) | (uint_t)iy1c;
        uint_t u10 = (__float_as_uint(c10) & ~127u) | (uint_t)ix0c;
        uint_t u11 = (__float_as_uint(c11) & ~127u) | (uint_t)ix1c;
        *(uint4*)&coefA[((size_t)t * 65536 + pix) * 4] = make_uint4(u00, u01, u10, u11);
    }
}

// Fused sample + bf16-split MFMA GEMM. Block = 8 waves, one (b,y) row (128 px).
// Wave w: samples px [16w,16w+16) (lane = channel), then GEMM m-tile w x 4 n-tiles.
__global__ __launch_bounds__(512, 4) void deform_main(
        const float* __restrict__ xt, const uint_t* __restrict__ coefA,
        const ushort_t* __restrict__ g_wbh, const ushort_t* __restrict__ g_wbl,
        const float* __restrict__ bias, float* __restrict__ out) {
    __shared__ __align__(16) ushort_t s_hi[128][72];       // 18,432 B
    __shared__ __align__(16) ushort_t s_lo[128][72];       // 18,432 B
    __shared__ __align__(16) ushort_t wb[2][2][64][72];    // 36,864 B

    int w = threadIdx.x >> 6, lane = threadIdx.x & 63;
    int col = lane & 15;
    int kgrp = lane >> 4;
    // XCD-aware swizzle: 512 = 8 XCDs x 64 contiguous (b,y) rows
    int blk = (blockIdx.x & 7) * 64 + (blockIdx.x >> 3);
    int b = blk >> 7, y = blk & 127;
    int pix0 = blk * 128;
    const float* xb = xt + (size_t)b * (NH * NW * NC);

    f32x4 acc[4];
#pragma unroll
    for (int n = 0; n < 4; ++n) {
        float bv = bias[n * 16 + col];
        acc[n] = (f32x4){bv, bv, bv, bv};
    }

    auto prefetchW = [&](int tap, int bi) {
        for (int j = w; j < 18; j += 8) {
            int hsel = (j < 9) ? 0 : 1;
            int j2 = (j < 9) ? j : j - 9;
            const ushort_t* src = (hsel ? g_wbl : g_wbh) + tap * 4608 + j2 * 512 + lane * 8;
            ushort_t* dst = &wb[bi][hsel][0][0] + j2 * 512;
            async_copy16(dst, src);
        }
    };

    prefetchW(0, 0);
    __syncthreads();

    for (int t = 0; t < 9; ++t) {
        // ---- sampling: 16 px per wave, lane = channel ----
#pragma unroll 4
        for (int p = 0; p < 16; ++p) {
            int rowi = w * 16 + p;
            int px = pix0 + rowi;
            uint4 cu = *(const uint4*)&coefA[((size_t)t * 65536 + px) * 4];
            float c00 = __uint_as_float(cu.x), c01 = __uint_as_float(cu.y);
            float c10 = __uint_as_float(cu.z), c11 = __uint_as_float(cu.w);
            int r0 = (int)(cu.x & 127u) << 13;   // iy0c * 128*64
            int r1 = (int)(cu.y & 127u) << 13;   // iy1c
            int q0 = (int)(cu.z & 127u) << 6;    // ix0c * 64
            int q1 = (int)(cu.w & 127u) << 6;    // ix1c
            float v00 = xb[r0 + q0 + lane];
            float v01 = xb[r0 + q1 + lane];
            float v10 = xb[r1 + q0 + lane];
            float v11 = xb[r1 + q1 + lane];
            float s = c00 * v00 + c01 * v01 + c10 * v10 + c11 * v11;
            ushort_t h, l;
            split_bf16(s, h, l);
            s_hi[rowi][lane] = h;
            s_lo[rowi][lane] = l;
        }
        if (t < 8) prefetchW(t + 1, (t + 1) & 1);
        __syncthreads();   // s tiles + wb[t] ready (prefetch t+1 in flight ok)

        // ---- GEMM: m-tile = w, 4 n-tiles, 6 k-steps (hh,hl,lh) ----
        {
            int bi = t & 1;
            short8 ah[2], al[2];
#pragma unroll
            for (int ks = 0; ks < 2; ++ks) {
                int row = w * 16 + col;
                ah[ks] = *(const short8*)&s_hi[row][ks * 32 + kgrp * 8];
                al[ks] = *(const short8*)&s_lo[row][ks * 32 + kgrp * 8];
            }
#pragma unroll
            for (int h = 0; h < 2; ++h) {     // n-halves to bound VGPR
                short8 bh[2][2], bl[2][2];
#pragma unroll
                for (int n2 = 0; n2 < 2; ++n2)
#pragma unroll
                    for (int ks = 0; ks < 2; ++ks) {
                        int o = (h * 2 + n2) * 16 + col;
                        bh[n2][ks] = *(const short8*)&wb[bi][0][o][ks * 32 + kgrp * 8];
                        bl[n2][ks] = *(const short8*)&wb[bi][1][o][ks * 32 + kgrp * 8];
                    }
#pragma unroll
                for (int n2 = 0; n2 < 2; ++n2) {
                    int n = h * 2 + n2;
                    acc[n] = __builtin_amdgcn_mfma_f32_16x16x32_bf16(ah[0], bh[n2][0], acc[n], 0, 0, 0);
                    acc[n] = __builtin_amdgcn_mfma_f32_16x16x32_bf16(ah[1], bh[n2][1], acc[n], 0, 0, 0);
                    acc[n] = __builtin_amdgcn_mfma_f32_16x16x32_bf16(ah[0], bl[n2][0], acc[n], 0, 0, 0);
                    acc[n] = __builtin_amdgcn_mfma_f32_16x16x32_bf16(ah[1], bl[n2][1], acc[n], 0, 0, 0);
                    acc[n] = __builtin_amdgcn_mfma_f32_16x16x32_bf16(al[0], bh[n2][0], acc[n], 0, 0, 0);
                    acc[n] = __builtin_amdgcn_mfma_f32_16x16x32_bf16(al[1], bh[n2][1], acc[n], 0, 0, 0);
                }
            }
        }
        __syncthreads();   // GEMM done before next tap overwrites s / wb buf
    }

#pragma unroll
    for (int n = 0; n < 4; ++n) {
        int o = n * 16 + col;
        int x = w * 16 + kgrp * 4;
        float* dst = out + (((size_t)(b * 64 + o)) * 128 + y) * 128 + x;
        *(f32x4*)dst = acc[n];
    }
}

extern "C" void kernel_launch(void* const* d_in, const int* in_sizes, int n_in,
                              void* d_out, int out_size, void* d_ws, size_t ws_size,
                              hipStream_t stream) {
    const float* x        = (const float*)d_in[0];
    const float* off_feat = (const float*)d_in[1];
    const float* w_off    = (const float*)d_in[2];
    const float* b_off    = (const float*)d_in[3];
    const float* weight   = (const float*)d_in[4];
    const float* bias     = (const float*)d_in[5];
    float* out = (float*)d_out;

    float* ws      = (float*)d_ws;
    float* xt      = ws;                          // 4,194,304
    uint_t* coefA  = (uint_t*)(ws + 4194304);     // 2,359,296
    float* wt_off  = ws + 6553600;                // 8,064
    ushort_t* g_wbh = (ushort_t*)(ws + 6561664);  // 41,472 ushorts
    ushort_t* g_wbl = (ushort_t*)(ws + 6582400);  // 41,472 ushorts

    prep_weights<<<194, 256, 0, stream>>>(weight, w_off, g_wbh, g_wbl, wt_off);
    transpose_x<<<512, 256, 0, stream>>>(x, xt);
    offset_conv<<<1024, 256, 0, stream>>>(off_feat, wt_off, b_off, coefA);
    deform_main<<<512, 512, 0, stream>>>(xt, coefA, g_wbh, g_wbl, bias, out);
}

// Round 9
// 193.252 us; speedup vs baseline: 2.4078x; 1.1423x over previous
//
#include <hip/hip_runtime.h>
#include <math.h>

typedef unsigned short ushort_t;
typedef unsigned int uint_t;
typedef __attribute__((ext_vector_type(8))) short short8;
typedef __attribute__((ext_vector_type(4))) float f32x4;

#define NB 4
#define NC 64
#define NH 128
#define NW 128
#define OFFC 32

// ws layout (float units) — total 6,603,136 floats = 26,412,544 B (r2/r4-proven).
//   xt     @ 0         : 4,194,304
//   coefA  @ 4194304   : 2,359,296  uint4/(tap,px): coef f32, idx in low 7 mantissa bits
//   wt_off @ 6553600   : 8,064
//   g_wbh  @ 6561664   : 20,736
//   g_wbl  @ 6582400   : 20,736

__device__ __forceinline__ void async_copy16(void* lds_dst, const void* g_src) {
    __builtin_amdgcn_global_load_lds(
        (const __attribute__((address_space(1))) unsigned int*)g_src,
        (__attribute__((address_space(3))) unsigned int*)lds_dst, 16, 0, 0);
}

__device__ __forceinline__ void split_bf16(float v, ushort_t& h, ushort_t& l) {
    uint_t bb = __float_as_uint(v);
    uint_t rr = bb + 0x7fffu + ((bb >> 16) & 1u);   // RNE for hi (weights path)
    h = (ushort_t)(rr >> 16);
    float hf = __uint_as_float(((uint_t)h) << 16);
    float lof = v - hf;
    l = (ushort_t)(__float_as_uint(lof) >> 16);
}

__global__ __launch_bounds__(256) void prep_weights(
        const float* __restrict__ weight, const float* __restrict__ w_off,
        ushort_t* __restrict__ g_wbh, ushort_t* __restrict__ g_wbl,
        float* __restrict__ wt_off) {
    int idx = blockIdx.x * 256 + threadIdx.x;
    if (idx < 9 * 64 * 72) {
        int k   = idx % 72;
        int o   = (idx / 72) % 64;
        int tap = idx / (72 * 64);
        float v = (k < 64) ? weight[(o * 64 + k) * 9 + tap] : 0.0f;
        ushort_t h, l;
        split_bf16(v, h, l);
        g_wbh[idx] = h;
        g_wbl[idx] = l;
    }
    int idx2 = idx - 9 * 64 * 72;
    if (idx2 >= 0 && idx2 < 32 * 9 * 28) {
        int oc  = idx2 % 28;
        int r   = idx2 / 28;
        int tap = r % 9;
        int ic  = r / 9;
        wt_off[idx2] = (oc < 27) ? w_off[(oc * 32 + ic) * 9 + tap] : 0.0f;
    }
}

// Fused: blocks [0,512) transpose x -> xt; blocks [512,1536) offset conv + coef pack.
__global__ __launch_bounds__(256) void aux_fused(
        const float* __restrict__ xin, float* __restrict__ xt,
        const float* __restrict__ feat, const float* __restrict__ wt_off,
        const float* __restrict__ b_off, uint_t* __restrict__ coefA) {
    __shared__ __align__(16) float smem[8320];   // 33,280 B (max of both uses)
    int bid = blockIdx.x;
    int t = threadIdx.x;
    if (bid < 512) {
        float (*lds)[130] = (float (*)[130])smem;
        int b = bid >> 7;
        int y = bid & 127;
        int xx = t & 127;
        int c0 = t >> 7;
#pragma unroll
        for (int it = 0; it < 32; ++it) {
            int c = it * 2 + c0;
            lds[c][xx] = xin[((b * 64 + c) * 128 + y) * 128 + xx];
        }
        __syncthreads();
#pragma unroll
        for (int it = 0; it < 32; ++it) {
            int flat = it * 256 + t;
            int c  = flat & 63;
            int x2 = flat >> 6;
            xt[((b * 128 + y) * 128 + x2) * 64 + c] = lds[c][x2];
        }
        return;
    }
    // ---- offset conv branch ----
    float (*red)[27][64] = (float (*)[27][64])smem;   // 27,648 B
    int wv = t >> 6, lane = t & 63;
    int pix = (bid - 512) * 64 + lane;
    int b = pix >> 14, y = (pix >> 7) & 127, x = pix & 127;
    float acc[27];
#pragma unroll
    for (int o = 0; o < 27; ++o) acc[o] = 0.0f;
    for (int ic = wv * 8; ic < wv * 8 + 8; ++ic) {
        float v[9];
#pragma unroll
        for (int kh = 0; kh < 3; ++kh) {
#pragma unroll
            for (int kw = 0; kw < 3; ++kw) {
                int yy = y - 1 + kh;
                int xx = x - 1 + kw;
                float valid = (yy >= 0 && yy < NH && xx >= 0 && xx < NW) ? 1.0f : 0.0f;
                int yyc = min(max(yy, 0), NH - 1);
                int xxc = min(max(xx, 0), NW - 1);
                v[kh * 3 + kw] = feat[((b * OFFC + ic) * NH + yyc) * NW + xxc] * valid;
            }
        }
#pragma unroll
        for (int tap = 0; tap < 9; ++tap)
#pragma unroll
            for (int o = 0; o < 27; ++o)
                acc[o] = fmaf(v[tap], wt_off[(ic * 9 + tap) * 28 + o], acc[o]);
    }
#pragma unroll
    for (int o = 0; o < 27; ++o) red[wv][o][lane] = acc[o];
    __syncthreads();
    for (int tp = wv; tp < 9; tp += 4) {
        float dy = red[0][2 * tp][lane] + red[1][2 * tp][lane]
                 + red[2][2 * tp][lane] + red[3][2 * tp][lane] + b_off[2 * tp];
        float dx = red[0][2 * tp + 1][lane] + red[1][2 * tp + 1][lane]
                 + red[2][2 * tp + 1][lane] + red[3][2 * tp + 1][lane] + b_off[2 * tp + 1];
        float mv = red[0][18 + tp][lane] + red[1][18 + tp][lane]
                 + red[2][18 + tp][lane] + red[3][18 + tp][lane] + b_off[18 + tp];
        float mm = 1.0f / (1.0f + __expf(-mv));
        float py  = (float)(y - 1 + tp / 3) + dy;
        float pxf = (float)(x - 1 + tp % 3) + dx;
        float y0f = floorf(py), x0f = floorf(pxf);
        float wy = py - y0f, wx = pxf - x0f;
        int iy0 = (int)y0f, ix0 = (int)x0f;
        int iy1 = iy0 + 1, ix1 = ix0 + 1;
        float vy0 = (iy0 >= 0 && iy0 < NH) ? 1.0f : 0.0f;
        float vy1 = (iy1 >= 0 && iy1 < NH) ? 1.0f : 0.0f;
        float vx0 = (ix0 >= 0 && ix0 < NW) ? 1.0f : 0.0f;
        float vx1 = (ix1 >= 0 && ix1 < NW) ? 1.0f : 0.0f;
        int iy0c = min(max(iy0, 0), NH - 1), iy1c = min(max(iy1, 0), NH - 1);
        int ix0c = min(max(ix0, 0), NW - 1), ix1c = min(max(ix1, 0), NW - 1);
        float c00 = (1.0f - wy) * (1.0f - wx) * vy0 * vx0 * mm;
        float c01 = (1.0f - wy) * wx * vy0 * vx1 * mm;
        float c10 = wy * (1.0f - wx) * vy1 * vx0 * mm;
        float c11 = wy * wx * vy1 * vx1 * mm;
        // coefs >= 0; clamped indices in low 7 mantissa bits (<=127 ulp perturbation).
        uint_t u00 = (__float_as_uint(c00) & ~127u) | (uint_t)iy0c;
        uint_t u01 = (__float_as_uint(c01) & ~127u) | (uint_t)iy1c;
        uint_t u10 = (__float_as_uint(c10) & ~127u) | (uint_t)ix0c;
        uint_t u11 = (__float_as_uint(c11) & ~127u) | (uint_t)ix1c;
        *(uint4*)&coefA[((size_t)tp * 65536 + pix) * 4] = make_uint4(u00, u01, u10, u11);
    }
}

// Fused sample + bf16-split MFMA GEMM. Block = 8 waves, one (b,y) row (128 px).
// Sampling scalarized: per (wave,tap) ONE coalesced coef load (lane l = word l of
// 16px x 4 corners), v_readlane -> SGPR unpack/addressing (SALU), saddr gathers.
__global__ __launch_bounds__(512, 4) void deform_main(
        const float* __restrict__ xt, const uint_t* __restrict__ coefA,
        const ushort_t* __restrict__ g_wbh, const ushort_t* __restrict__ g_wbl,
        const float* __restrict__ bias, float* __restrict__ out) {
    __shared__ __align__(16) ushort_t s_hi[128][72];       // 18,432 B
    __shared__ __align__(16) ushort_t s_lo[128][72];       // 18,432 B
    __shared__ __align__(16) ushort_t wb[2][2][64][72];    // 36,864 B

    int lane = threadIdx.x & 63;
    int wu = __builtin_amdgcn_readfirstlane(threadIdx.x >> 6);  // uniform wave id
    int col = lane & 15;
    int kgrp = lane >> 4;
    int blk = (blockIdx.x & 7) * 64 + (blockIdx.x >> 3);   // XCD swizzle (512=8x64)
    int b = blk >> 7, y = blk & 127;
    int pix0 = blk * 128;
    const float* xb = xt + (size_t)b * (NH * NW * NC);

    f32x4 acc[4];
#pragma unroll
    for (int n = 0; n < 4; ++n) {
        float bv = bias[n * 16 + col];
        acc[n] = (f32x4){bv, bv, bv, bv};
    }

    auto prefetchW = [&](int tap, int bi) {
        for (int j = wu; j < 18; j += 8) {
            int hsel = (j < 9) ? 0 : 1;
            int j2 = (j < 9) ? j : j - 9;
            const ushort_t* src = (hsel ? g_wbl : g_wbh) + tap * 4608 + j2 * 512 + lane * 8;
            ushort_t* dst = &wb[bi][hsel][0][0] + j2 * 512;
            async_copy16(dst, src);
        }
    };

    prefetchW(0, 0);
    __syncthreads();

    for (int t = 0; t < 9; ++t) {
        // ---- sampling: 16 px per wave; coef words for all 16 px in one load ----
        uint_t cw = coefA[((size_t)t * 65536 + pix0) * 4 + wu * 64 + lane];
#pragma unroll
        for (int p = 0; p < 16; ++p) {
            uint_t u00 = (uint_t)__builtin_amdgcn_readlane((int)cw, 4 * p + 0);
            uint_t u01 = (uint_t)__builtin_amdgcn_readlane((int)cw, 4 * p + 1);
            uint_t u10 = (uint_t)__builtin_amdgcn_readlane((int)cw, 4 * p + 2);
            uint_t u11 = (uint_t)__builtin_amdgcn_readlane((int)cw, 4 * p + 3);
            float c00 = __uint_as_float(u00 & ~127u);
            float c01 = __uint_as_float(u01 & ~127u);
            float c10 = __uint_as_float(u10 & ~127u);
            float c11 = __uint_as_float(u11 & ~127u);
            const float* r0 = xb + ((u00 & 127u) << 13);   // iy0c row base
            const float* r1 = xb + ((u01 & 127u) << 13);   // iy1c row base
            uint_t q0 = (u10 & 127u) << 6;                 // ix0c * 64
            uint_t q1 = (u11 & 127u) << 6;                 // ix1c * 64
            const float* p00 = r0 + q0;
            const float* p01 = r0 + q1;
            const float* p10 = r1 + q0;
            const float* p11 = r1 + q1;
            float v00 = p00[lane];
            float v01 = p01[lane];
            float v10 = p10[lane];
            float v11 = p11[lane];
            float s = c00 * v00;
            s = fmaf(c01, v01, s);
            s = fmaf(c10, v10, s);
            s = fmaf(c11, v11, s);
            // truncate-split: v = hi + lo exactly; lo trunc to bf16 (err <= 2^-16 |v|)
            uint_t sb = __float_as_uint(s);
            float lof = s - __uint_as_float(sb & 0xffff0000u);
            int rowi = wu * 16 + p;
            s_hi[rowi][lane] = (ushort_t)(sb >> 16);
            s_lo[rowi][lane] = (ushort_t)(__float_as_uint(lof) >> 16);
        }
        if (t < 8) prefetchW(t + 1, (t + 1) & 1);
        __syncthreads();   // s tiles + wb[t] ready (prefetch t+1 in flight ok)

        // ---- GEMM: m-tile = wu, 4 n-tiles, 6 k-steps (hh,hl,lh) ----
        {
            int bi = t & 1;
            short8 ah[2], al[2];
#pragma unroll
            for (int ks = 0; ks < 2; ++ks) {
                int row = wu * 16 + col;
                ah[ks] = *(const short8*)&s_hi[row][ks * 32 + kgrp * 8];
                al[ks] = *(const short8*)&s_lo[row][ks * 32 + kgrp * 8];
            }
#pragma unroll
            for (int h = 0; h < 2; ++h) {
                short8 bh[2][2], bl[2][2];
#pragma unroll
                for (int n2 = 0; n2 < 2; ++n2)
#pragma unroll
                    for (int ks = 0; ks < 2; ++ks) {
                        int o = (h * 2 + n2) * 16 + col;
                        bh[n2][ks] = *(const short8*)&wb[bi][0][o][ks * 32 + kgrp * 8];
                        bl[n2][ks] = *(const short8*)&wb[bi][1][o][ks * 32 + kgrp * 8];
                    }
#pragma unroll
                for (int n2 = 0; n2 < 2; ++n2) {
                    int n = h * 2 + n2;
                    acc[n] = __builtin_amdgcn_mfma_f32_16x16x32_bf16(ah[0], bh[n2][0], acc[n], 0, 0, 0);
                    acc[n] = __builtin_amdgcn_mfma_f32_16x16x32_bf16(ah[1], bh[n2][1], acc[n], 0, 0, 0);
                    acc[n] = __builtin_amdgcn_mfma_f32_16x16x32_bf16(ah[0], bl[n2][0], acc[n], 0, 0, 0);
                    acc[n] = __builtin_amdgcn_mfma_f32_16x16x32_bf16(ah[1], bl[n2][1], acc[n], 0, 0, 0);
                    acc[n] = __builtin_amdgcn_mfma_f32_16x16x32_bf16(al[0], bh[n2][0], acc[n], 0, 0, 0);
                    acc[n] = __builtin_amdgcn_mfma_f32_16x16x32_bf16(al[1], bh[n2][1], acc[n], 0, 0, 0);
                }
            }
        }
        __syncthreads();   // GEMM done before next tap overwrites s / wb buf
    }

#pragma unroll
    for (int n = 0; n < 4; ++n) {
        int o = n * 16 + col;
        int x = wu * 16 + kgrp * 4;
        float* dst = out + (((size_t)(b * 64 + o)) * 128 + y) * 128 + x;
        *(f32x4*)dst = acc[n];
    }
}

extern "C" void kernel_launch(void* const* d_in, const int* in_sizes, int n_in,
                              void* d_out, int out_size, void* d_ws, size_t ws_size,
                              hipStream_t stream) {
    const float* x        = (const float*)d_in[0];
    const float* off_feat = (const float*)d_in[1];
    const float* w_off    = (const float*)d_in[2];
    const float* b_off    = (const float*)d_in[3];
    const float* weight   = (const float*)d_in[4];
    const float* bias     = (const float*)d_in[5];
    float* out = (float*)d_out;

    float* ws      = (float*)d_ws;
    float* xt      = ws;                          // 4,194,304
    uint_t* coefA  = (uint_t*)(ws + 4194304);     // 2,359,296
    float* wt_off  = ws + 6553600;                // 8,064
    ushort_t* g_wbh = (ushort_t*)(ws + 6561664);  // 41,472 ushorts
    ushort_t* g_wbl = (ushort_t*)(ws + 6582400);  // 41,472 ushorts

    prep_weights<<<194, 256, 0, stream>>>(weight, w_off, g_wbh, g_wbl, wt_off);
    aux_fused<<<1536, 256, 0, stream>>>(x, xt, off_feat, wt_off, b_off, coefA);
    deform_main<<<512, 512, 0, stream>>>(xt, coefA, g_wbh, g_wbl, bias, out);
}